// Round 4
// baseline (299.542 us; speedup 1.0000x reference)
//
#include <hip/hip_runtime.h>
#include <math.h>

constexpr int B_  = 128;
constexpr int A_  = 2048;
constexpr int C_  = 128;
constexpr int H_  = 512;
constexpr int S_  = 3;
constexpr int NR_ = 2;
constexpr int PR_ = C_ + 3 + S_;      // 134
constexpr int PW_ = 3 * C_ + 3 + S_;  // 390
constexpr int NOUT_ = NR_ * PR_ + PW_;  // 658 projection outputs per batch

typedef float vfloat4 __attribute__((ext_vector_type(4)));

__device__ __forceinline__ float sigmoidf_(float x) { return 1.0f / (1.0f + expf(-x)); }
__device__ __forceinline__ float softplusf_(float x) {
  return fmaxf(x, 0.0f) + log1pf(expf(-fabsf(x)));
}

__device__ __forceinline__ float waveReduceSum(float v) {
#pragma unroll
  for (int off = 32; off; off >>= 1) v += __shfl_xor(v, off, 64);
  return v;
}
__device__ __forceinline__ float waveReduceMax(float v) {
#pragma unroll
  for (int off = 32; off; off >>= 1) v = fmaxf(v, __shfl_xor(v, off, 64));
  return v;
}

// blockDim == 256 (4 waves)
__device__ __forceinline__ float blockReduceSum(float v, float* rbuf) {
  int tid = threadIdx.x;
  v = waveReduceSum(v);
  if ((tid & 63) == 0) rbuf[tid >> 6] = v;
  __syncthreads();
  float r = rbuf[0] + rbuf[1] + rbuf[2] + rbuf[3];
  __syncthreads();
  return r;
}
__device__ __forceinline__ float blockReduceMax(float v, float* rbuf) {
  int tid = threadIdx.x;
  v = waveReduceMax(v);
  if ((tid & 63) == 0) rbuf[tid >> 6] = v;
  __syncthreads();
  float r = fmaxf(fmaxf(rbuf[0], rbuf[1]), fmaxf(rbuf[2], rbuf[3]));
  __syncthreads();
  return r;
}

// ---------------------------------------------------------------------------
// Kernel 1 (v3): projections. grid = 32 b-groups x 8 output-slices = 256
// blocks. Each block stages h for 4 batches in LDS (8 KB) and reads each of
// its ~83 W rows ONCE, reusing it for all 4 batches -> W L2 traffic 345->43MB.
// Wave j computes output o = j*8 + slice for 4 batches (4 wave-reduces).
// Also zeroes the rv accumulator (NR*B*C = 32768 floats).
// ---------------------------------------------------------------------------
__global__ __launch_bounds__(256) void proj_kernel(
    const float* __restrict__ h, const float* __restrict__ Wr,
    const float* __restrict__ br, const float* __restrict__ Ww,
    const float* __restrict__ bw, float* __restrict__ pr,
    float* __restrict__ pw, float* __restrict__ rv) {
  __shared__ __align__(16) float4 hs4[4 * (H_ / 4)];   // 4 batches x 128 float4
  int bg = blockIdx.x >> 3;       // batch group (4 batches)
  int slice = blockIdx.x & 7;     // output slice
  int tid = threadIdx.x;

  // fused rv zeroing: 256 blocks x 256 threads = 65536 >= 32768
  int gid = blockIdx.x * 256 + tid;
  if (gid < NR_ * B_ * C_) rv[gid] = 0.0f;

  const float4* h4g = (const float4*)h;
  for (int i = tid; i < 512; i += 256) {
    int bl = i >> 7;              // local batch 0..3
    int f = i & 127;
    hs4[i] = h4g[((size_t)(bg * 4 + bl)) * (H_ / 4) + f];
  }
  __syncthreads();

  int wv = tid >> 6;
  int lane = tid & 63;
  // loop-invariant h fragments: quads lane and lane+64 for each local batch
  float4 hv[4][2];
#pragma unroll
  for (int bl = 0; bl < 4; bl++) {
    hv[bl][0] = hs4[bl * 128 + lane];
    hv[bl][1] = hs4[bl * 128 + 64 + lane];
  }

  for (int j = wv; j * 8 + slice < NOUT_; j += 4) {
    int o = j * 8 + slice;
    const float* wrow;
    float bias;
    if (o < NR_ * PR_) {
      wrow = Wr + (size_t)o * H_;   // row (r*PR+p) == o
      bias = br[o];
    } else {
      wrow = Ww + (size_t)(o - NR_ * PR_) * H_;
      bias = bw[o - NR_ * PR_];
    }
    const float4* w4 = (const float4*)wrow;
    float4 w0 = w4[lane];
    float4 w1 = w4[lane + 64];
    float acc[4];
#pragma unroll
    for (int bl = 0; bl < 4; bl++) {
      float a = hv[bl][0].x * w0.x;
      a = fmaf(hv[bl][0].y, w0.y, a);
      a = fmaf(hv[bl][0].z, w0.z, a);
      a = fmaf(hv[bl][0].w, w0.w, a);
      a = fmaf(hv[bl][1].x, w1.x, a);
      a = fmaf(hv[bl][1].y, w1.y, a);
      a = fmaf(hv[bl][1].z, w1.z, a);
      a = fmaf(hv[bl][1].w, w1.w, a);
      acc[bl] = waveReduceSum(a);
    }
    if (lane == 0) {
#pragma unroll
      for (int bl = 0; bl < 4; bl++) {
        int b = bg * 4 + bl;
        if (o < NR_ * PR_) {
          int r = (o >= PR_) ? 1 : 0;
          int p = o - r * PR_;
          pr[((size_t)(r * B_ + b)) * PR_ + p] = acc[bl] + bias;
        } else {
          pw[(size_t)b * PW_ + (o - NR_ * PR_)] = acc[bl] + bias;
        }
      }
    }
  }
}

// ---------------------------------------------------------------------------
// Kernel 2: sim pass over mem, with INLINE q/qn computation from pr/pw
// (headprep kernel eliminated). grid = B * A/64 = 4096, block 256.
// ---------------------------------------------------------------------------
__global__ __launch_bounds__(256) void sim_kernel(
    const float* __restrict__ mem, const float* __restrict__ pr,
    const float* __restrict__ pw, float* __restrict__ sim) {
  __shared__ __align__(16) float qs[3 * C_];
  __shared__ float qnl[3];
  int b = blockIdx.x >> 5;
  int chunk = blockIdx.x & 31;
  int rowbase = chunk << 6;
  int tid = threadIdx.x;

  // waves 0..2 each handle one head: sigmoid + norm (64 lanes x 2 elems)
  if (tid < 192) {
    int hd = tid >> 6;
    int c2 = (tid & 63) << 1;
    const float* src = (hd < 2) ? (pr + ((size_t)(hd * B_ + b)) * PR_)
                                : (pw + (size_t)b * PW_);
    float2 raw = *(const float2*)(src + c2);
    float q0 = sigmoidf_(raw.x);
    float q1 = sigmoidf_(raw.y);
    qs[hd * C_ + c2] = q0;
    qs[hd * C_ + c2 + 1] = q1;
    float ss = waveReduceSum(q0 * q0 + q1 * q1);
    if ((tid & 63) == 0) qnl[hd] = fmaxf(sqrtf(ss), 1e-8f);
  }
  __syncthreads();

  int wv = tid >> 6;
  int lane = tid & 63;
  int j = lane & 7;       // 8 lanes per row
  int rsub = lane >> 3;

  float4 q0[4], q1[4], q2[4];
  const float4* qs4 = (const float4*)qs;
#pragma unroll
  for (int k = 0; k < 4; k++) {
    q0[k] = qs4[j + 8 * k];
    q1[k] = qs4[32 + j + 8 * k];
    q2[k] = qs4[64 + j + 8 * k];
  }
  float iqn0 = 1.0f / qnl[0], iqn1 = 1.0f / qnl[1], iqn2 = 1.0f / qnl[2];

#pragma unroll
  for (int it = 0; it < 2; it++) {
    int row = rowbase + (it << 5) + (wv << 3) + rsub;
    const float4* mrow = (const float4*)(mem + ((size_t)b * A_ + row) * C_);
    float d0 = 0.f, d1 = 0.f, d2 = 0.f, ss = 0.f;
#pragma unroll
    for (int k = 0; k < 4; k++) {
      float4 m = mrow[j + 8 * k];
      d0 = fmaf(m.x, q0[k].x, d0); d0 = fmaf(m.y, q0[k].y, d0);
      d0 = fmaf(m.z, q0[k].z, d0); d0 = fmaf(m.w, q0[k].w, d0);
      d1 = fmaf(m.x, q1[k].x, d1); d1 = fmaf(m.y, q1[k].y, d1);
      d1 = fmaf(m.z, q1[k].z, d1); d1 = fmaf(m.w, q1[k].w, d1);
      d2 = fmaf(m.x, q2[k].x, d2); d2 = fmaf(m.y, q2[k].y, d2);
      d2 = fmaf(m.z, q2[k].z, d2); d2 = fmaf(m.w, q2[k].w, d2);
      ss = fmaf(m.x, m.x, ss); ss = fmaf(m.y, m.y, ss);
      ss = fmaf(m.z, m.z, ss); ss = fmaf(m.w, m.w, ss);
    }
#pragma unroll
    for (int off = 1; off <= 4; off <<= 1) {
      d0 += __shfl_xor(d0, off, 64);
      d1 += __shfl_xor(d1, off, 64);
      d2 += __shfl_xor(d2, off, 64);
      ss += __shfl_xor(ss, off, 64);
    }
    if (j == 0) {
      float imn = 1.0f / fmaxf(sqrtf(ss), 1e-8f);
      sim[(size_t)(0 * B_ + b) * A_ + row] = d0 * iqn0 * imn;
      sim[(size_t)(1 * B_ + b) * A_ + row] = d1 * iqn1 * imn;
      sim[(size_t)(2 * B_ + b) * A_ + row] = d2 * iqn2 * imn;
    }
  }
}

// ---------------------------------------------------------------------------
// Kernel 3: attention per (head,b), scalar params computed INLINE from pr/pw.
// Writes IN-PLACE over sim. grid = 3*B = 384, block 256.
// ---------------------------------------------------------------------------
__global__ __launch_bounds__(256) void attn_kernel(
    const float* __restrict__ sim, const float* __restrict__ ra,
    const float* __restrict__ wa, const float* __restrict__ pr,
    const float* __restrict__ pw, float* __restrict__ attn) {
  __shared__ float wg[A_];
  __shared__ float rbuf[4];
  __shared__ float pp[6];
  int hb = blockIdx.x;
  int hd = hb >> 7;
  int b = hb & (B_ - 1);
  int tid = threadIdx.x;
  const float* src = (hd < 2) ? (pr + (size_t)hb * PR_) : (pw + (size_t)b * PW_);
  if (tid == 0) {
    float braw = src[C_];
    float graw = src[C_ + 1];
    float s0 = src[C_ + 2], s1 = src[C_ + 3], s2 = src[C_ + 4];
    float gmraw = src[C_ + 5];
    float mx3 = fmaxf(s0, fmaxf(s1, s2));
    float e0 = expf(s0 - mx3), e1 = expf(s1 - mx3), e2 = expf(s2 - mx3);
    float inv3 = 1.0f / (e0 + e1 + e2);
    pp[0] = softplusf_(braw) + 1.0f;   // beta
    pp[1] = sigmoidf_(graw);           // gate
    pp[2] = e0 * inv3;
    pp[3] = e1 * inv3;
    pp[4] = e2 * inv3;
    pp[5] = softplusf_(gmraw) + 1.0f;  // gamma
  }
  const float* simrow = sim + (size_t)hb * A_;
  const float* prev = (hd < 2) ? (ra + (size_t)hb * A_) : (wa + (size_t)b * A_);
  float* outrow = attn + (size_t)hb * A_;

  float s[8];
  float mx = -1e30f;
#pragma unroll
  for (int i = 0; i < 8; i++) {
    s[i] = simrow[tid + (i << 8)];
    mx = fmaxf(mx, s[i]);
  }
  mx = blockReduceMax(mx, rbuf);   // contains __syncthreads -> pp visible after
  float beta = pp[0], gate = pp[1], sw0 = pp[2], sw1 = pp[3], sw2 = pp[4], gamma = pp[5];
  float p[8];
  float lsum = 0.0f;
#pragma unroll
  for (int i = 0; i < 8; i++) {
    p[i] = expf(beta * (s[i] - mx));
    lsum += p[i];
  }
  float tot = blockReduceSum(lsum, rbuf);
  float inv = 1.0f / tot;
#pragma unroll
  for (int i = 0; i < 8; i++) {
    int a = tid + (i << 8);
    wg[a] = fmaf(gate, p[i] * inv, (1.0f - gate) * prev[a]);
  }
  __syncthreads();
  float lsum2 = 0.0f;
#pragma unroll
  for (int i = 0; i < 8; i++) {
    int a = tid + (i << 8);
    float ws = sw0 * wg[(a + 1) & (A_ - 1)] + sw1 * wg[a] + sw2 * wg[(a - 1) & (A_ - 1)];
    float wp = (ws > 0.0f) ? exp2f(gamma * log2f(ws)) : 0.0f;
    p[i] = wp;
    lsum2 += wp;
  }
  float tot2 = blockReduceSum(lsum2, rbuf);
  float inv2 = 1.0f / (tot2 + 1e-12f);
#pragma unroll
  for (int i = 0; i < 8; i++) {
    outrow[tid + (i << 8)] = p[i] * inv2;
  }
}

// ---------------------------------------------------------------------------
// Kernel 4: second pass over mem. read_vectors + new_mem. Nontemporal stores
// for new_mem keep `mem` L3-resident for this kernel's own reads.
// ---------------------------------------------------------------------------
__global__ __launch_bounds__(256) void update_kernel(
    const float* __restrict__ mem, const float* __restrict__ attn,
    const float* __restrict__ pw, float* __restrict__ rv,
    float* __restrict__ nmem) {
  __shared__ float att0[256], att1[256], attw[256];
  __shared__ float4 red0[256];
  __shared__ float4 red1[256];
  int b = blockIdx.x >> 3;
  int chunk = blockIdx.x & 7;
  int rowbase = chunk << 8;
  int tid = threadIdx.x;
  att0[tid] = attn[(size_t)(0 * B_ + b) * A_ + rowbase + tid];
  att1[tid] = attn[(size_t)(1 * B_ + b) * A_ + rowbase + tid];
  attw[tid] = attn[(size_t)(2 * B_ + b) * A_ + rowbase + tid];
  __syncthreads();

  int rowlane = tid & 31;
  int rowoff = tid >> 5;
  int c0 = rowlane << 2;
  const float* pwrow = pw + (size_t)b * PW_;
  float2 eA = *(const float2*)(pwrow + C_ + 6 + c0);        // erase at offset 134
  float2 eB = *(const float2*)(pwrow + C_ + 6 + c0 + 2);
  float2 aA = *(const float2*)(pwrow + 2 * C_ + 6 + c0);    // add at offset 262
  float2 aB = *(const float2*)(pwrow + 2 * C_ + 6 + c0 + 2);
  float e0 = sigmoidf_(eA.x), e1 = sigmoidf_(eA.y), e2 = sigmoidf_(eB.x), e3 = sigmoidf_(eB.y);
  float ad0 = sigmoidf_(aA.x), ad1 = sigmoidf_(aA.y), ad2 = sigmoidf_(aB.x), ad3 = sigmoidf_(aB.y);

  float4 acc0 = make_float4(0.f, 0.f, 0.f, 0.f);
  float4 acc1 = make_float4(0.f, 0.f, 0.f, 0.f);

#pragma unroll 4
  for (int i = 0; i < 32; i++) {
    int ridx = (i << 3) + rowoff;
    int row = rowbase + ridx;
    size_t base = ((size_t)b * A_ + row) * C_ + c0;
    float4 m = *(const float4*)(mem + base);
    float w0 = att0[ridx];
    float w1 = att1[ridx];
    float ww = attw[ridx];
    acc0.x = fmaf(w0, m.x, acc0.x);
    acc0.y = fmaf(w0, m.y, acc0.y);
    acc0.z = fmaf(w0, m.z, acc0.z);
    acc0.w = fmaf(w0, m.w, acc0.w);
    acc1.x = fmaf(w1, m.x, acc1.x);
    acc1.y = fmaf(w1, m.y, acc1.y);
    acc1.z = fmaf(w1, m.z, acc1.z);
    acc1.w = fmaf(w1, m.w, acc1.w);
    vfloat4 nm;
    nm.x = fmaf(m.x, 1.0f - ww * e0, ww * ad0);
    nm.y = fmaf(m.y, 1.0f - ww * e1, ww * ad1);
    nm.z = fmaf(m.z, 1.0f - ww * e2, ww * ad2);
    nm.w = fmaf(m.w, 1.0f - ww * e3, ww * ad3);
    __builtin_nontemporal_store(nm, (vfloat4*)(nmem + base));
  }

  red0[tid] = acc0;
  red1[tid] = acc1;
  __syncthreads();
#pragma unroll
  for (int s = 128; s >= 32; s >>= 1) {
    if (tid < s) {
      float4 x = red0[tid], y = red0[tid + s];
      x.x += y.x; x.y += y.y; x.z += y.z; x.w += y.w;
      red0[tid] = x;
      float4 u = red1[tid], v = red1[tid + s];
      u.x += v.x; u.y += v.y; u.z += v.z; u.w += v.w;
      red1[tid] = u;
    }
    __syncthreads();
  }
  if (tid < 32) {
    float4 r0 = red0[tid];
    float4 r1 = red1[tid];
    float* rv0 = rv + (size_t)(0 * B_ + b) * C_ + (tid << 2);
    float* rv1 = rv + (size_t)(1 * B_ + b) * C_ + (tid << 2);
    atomicAdd(rv0 + 0, r0.x);
    atomicAdd(rv0 + 1, r0.y);
    atomicAdd(rv0 + 2, r0.z);
    atomicAdd(rv0 + 3, r0.w);
    atomicAdd(rv1 + 0, r1.x);
    atomicAdd(rv1 + 1, r1.y);
    atomicAdd(rv1 + 2, r1.z);
    atomicAdd(rv1 + 3, r1.w);
  }
}

extern "C" void kernel_launch(void* const* d_in, const int* in_sizes, int n_in,
                              void* d_out, int out_size, void* d_ws, size_t ws_size,
                              hipStream_t stream) {
  const float* h   = (const float*)d_in[0];
  const float* mem = (const float*)d_in[1];
  const float* ra  = (const float*)d_in[2];
  const float* wa  = (const float*)d_in[3];
  const float* Wr  = (const float*)d_in[4];
  const float* br  = (const float*)d_in[5];
  const float* Ww  = (const float*)d_in[6];
  const float* bw  = (const float*)d_in[7];

  float* out = (float*)d_out;
  float* rv = out;                               // [NR][B][C]
  float* nmem = out + NR_ * B_ * C_;             // [B][A][C]

  float* ws = (float*)d_ws;
  float* pr_buf = ws;                            // NR*B*PR   = 34304
  float* pw_buf = pr_buf + NR_ * B_ * PR_;       // B*PW      = 49920
  float* simb   = pw_buf + B_ * PW_;             // 3*B*A     = 786432 (attn in-place)

  proj_kernel<<<dim3(256), dim3(256), 0, stream>>>(h, Wr, br, Ww, bw, pr_buf, pw_buf, rv);
  sim_kernel<<<dim3(B_ * (A_ / 64)), dim3(256), 0, stream>>>(mem, pr_buf, pw_buf, simb);
  attn_kernel<<<dim3(3 * B_), dim3(256), 0, stream>>>(simb, ra, wa, pr_buf, pw_buf, simb);
  update_kernel<<<dim3(B_ * (A_ / 256)), dim3(256), 0, stream>>>(mem, simb, pw_buf, rv, nmem);
}